// Round 7
// baseline (243.393 us; speedup 1.0000x reference)
//
#include <hip/hip_runtime.h>

typedef unsigned int uint;
typedef unsigned short ushort;
typedef short s8v __attribute__((ext_vector_type(8)));   // 8 bf16 (4 VGPRs)
typedef float f4v __attribute__((ext_vector_type(4)));   // 4 f32 acc

#define BSHIFT 8                 // 256 nodes per bucket
#define NBUCK_MAX 512
#define PART_CH 8192             // edges per partition block

// ---------------- bf16 helpers ----------------

__device__ __forceinline__ uint f2bf(float f) {       // RNE round to bf16, low 16
    uint b = __float_as_uint(f);
    return (b + 0x7fffu + ((b >> 16) & 1u)) >> 16;
}
__device__ __forceinline__ uint pack2(float a, float b) {
    return f2bf(a) | (f2bf(b) << 16);
}
__device__ __forceinline__ float bflo(uint u) { return __uint_as_float(u << 16); }
__device__ __forceinline__ float bfhi(uint u) { return __uint_as_float(u & 0xffff0000u); }

// ---------------- bucketed CSR build (no per-edge global atomics) ----------------

__global__ __launch_bounds__(256) void hist_k(const int* __restrict__ dst, int E, int nbuck,
                                              int* __restrict__ bcnt) {
    __shared__ int h[NBUCK_MAX];
    int t = threadIdx.x;
    for (int i = t; i < nbuck; i += 256) h[i] = 0;
    __syncthreads();
    int e0 = blockIdx.x * PART_CH;
    int e1 = min(e0 + PART_CH, E);
    for (int e = e0 + t; e < e1; e += 256) atomicAdd(&h[((uint)dst[e]) >> BSHIFT], 1);
    __syncthreads();
    for (int i = t; i < nbuck; i += 256) {
        int v = h[i];
        if (v) atomicAdd(&bcnt[i], v);
    }
}

__global__ __launch_bounds__(512) void bscan_k(const int* __restrict__ bcnt, int nbuck, int E,
                                               int* __restrict__ bo, int* __restrict__ bcur) {
    __shared__ int s[512];
    int t = threadIdx.x;
    int v = (t < nbuck) ? bcnt[t] : 0;
    s[t] = v;
    __syncthreads();
    for (int off = 1; off < 512; off <<= 1) {
        int x = (t >= off) ? s[t - off] : 0;
        __syncthreads();
        s[t] += x;
        __syncthreads();
    }
    int excl = s[t] - v;
    if (t < nbuck) { bo[t] = excl; bcur[t] = excl; }
    if (t == 0) bo[nbuck] = E;
}

__global__ __launch_bounds__(256) void part_k(const int* __restrict__ src,
                                              const int* __restrict__ dst, int E, int nbuck,
                                              int* __restrict__ bcur, uint* __restrict__ eb) {
    __shared__ int h[NBUCK_MAX];
    __shared__ int cur[NBUCK_MAX];
    int t = threadIdx.x;
    for (int i = t; i < nbuck; i += 256) h[i] = 0;
    __syncthreads();
    int e0 = blockIdx.x * PART_CH;
    int e1 = min(e0 + PART_CH, E);
    for (int e = e0 + t; e < e1; e += 256) atomicAdd(&h[((uint)dst[e]) >> BSHIFT], 1);
    __syncthreads();
    for (int i = t; i < nbuck; i += 256) {
        int v = h[i];
        cur[i] = v ? atomicAdd(&bcur[i], v) : 0;
    }
    __syncthreads();
    for (int e = e0 + t; e < e1; e += 256) {
        int d = dst[e];
        int b = ((uint)d) >> BSHIFT;
        int p = atomicAdd(&cur[b], 1);           // LDS atomic: cheap
        eb[p] = ((uint)src[e] << BSHIFT) | (uint)(d & 255);
    }
}

// one block per bucket: exact per-node counts, rowptr, dinv, and CSR fill
__global__ __launch_bounds__(256) void build_k(const uint* __restrict__ eb,
                                               const int* __restrict__ bo, int N, int E,
                                               int* __restrict__ rowptr,
                                               float* __restrict__ dinv,
                                               int* __restrict__ csr) {
    __shared__ int c[256];
    __shared__ int s[256];
    int b = blockIdx.x;
    int t = threadIdx.x;
    int node0 = b << BSHIFT;
    int beg = bo[b], end = bo[b + 1];
    c[t] = 0;
    __syncthreads();
    for (int e = beg + t; e < end; e += 256) atomicAdd(&c[eb[e] & 255], 1);
    __syncthreads();
    int v = c[t];
    s[t] = v;
    __syncthreads();
    for (int off = 1; off < 256; off <<= 1) {
        int x = (t >= off) ? s[t - off] : 0;
        __syncthreads();
        s[t] += x;
        __syncthreads();
    }
    int excl = s[t] - v;
    int node = node0 + t;
    if (node < N) {
        rowptr[node] = beg + excl;
        dinv[node] = rsqrtf((float)(1 + v));
    }
    if (b == 0 && t == 0) rowptr[N] = E;
    __syncthreads();
    c[t] = beg + excl;                 // reuse as absolute cursor per node
    __syncthreads();
    for (int e = beg + t; e < end; e += 256) {
        uint pk = eb[e];
        int p = atomicAdd(&c[pk & 255], 1);    // LDS atomic
        csr[p] = (int)(pk >> BSHIFT);
    }
}

// ---------------- W transpose+convert: W[128][OUTC] f32 -> Wt[OUTC][128] bf16 ----------------

template <int OUTC>
__global__ void wtrans_k(const float* __restrict__ W, ushort* __restrict__ Wt) {
    int c = blockIdx.x * 64 + threadIdx.x;
    if (c >= OUTC) return;
    for (int k0 = 0; k0 < 128; k0 += 8) {
        float v[8];
#pragma unroll
        for (int i = 0; i < 8; ++i) v[i] = W[(size_t)(k0 + i) * OUTC + c];
        uint4 p;
        p.x = pack2(v[0], v[1]);
        p.y = pack2(v[2], v[3]);
        p.z = pack2(v[4], v[5]);
        p.w = pack2(v[6], v[7]);
        *(uint4*)(Wt + (size_t)c * 128 + k0) = p;
    }
}

// ---------------- MFMA GEMM: hs (slice-planes, bf16) = dinv[row] * (A[N x 128] @ W) --------
// hs layout: NT planes of [N][16] bf16 (plane nt = output cols 16nt..16nt+15).

template <int OUTC, bool AF32>
__global__ __launch_bounds__(256) void gemm_mfma(const void* __restrict__ Ain,
                                                 const ushort* __restrict__ Wt,
                                                 const float* __restrict__ dinv,
                                                 ushort* __restrict__ hs, int N) {
    constexpr int NT = OUTC / 16;
    constexpr int LDK = 136;
    __shared__ ushort Al[64 * LDK];
    __shared__ ushort Wl[OUTC * LDK];

    int tid = threadIdx.x;
    int row0 = blockIdx.x * 64;

    {
        int r = tid >> 2, seg = tid & 3;
        int gr = row0 + r;
        if (gr > N - 1) gr = N - 1;
        ushort* dstp = &Al[r * LDK + seg * 32];
        if (AF32) {
            const float4* ap = (const float4*)((const float*)Ain + (size_t)gr * 128 + seg * 32);
#pragma unroll
            for (int i = 0; i < 4; ++i) {
                float4 f0 = ap[2 * i], f1 = ap[2 * i + 1];
                uint4 u;
                u.x = pack2(f0.x, f0.y);
                u.y = pack2(f0.z, f0.w);
                u.z = pack2(f1.x, f1.y);
                u.w = pack2(f1.z, f1.w);
                *(uint4*)(dstp + i * 8) = u;
            }
        } else {
            const uint4* ap = (const uint4*)((const ushort*)Ain + (size_t)gr * 128 + seg * 32);
#pragma unroll
            for (int i = 0; i < 4; ++i) *(uint4*)(dstp + i * 8) = ap[i];
        }
    }
    {
        const uint4* wp = (const uint4*)Wt;
        for (int idx = tid; idx < OUTC * 16; idx += 256) {
            int r = idx >> 4, c = idx & 15;
            *(uint4*)(&Wl[r * LDK + c * 8]) = wp[idx];
        }
    }
    __syncthreads();

    int w = tid >> 6;
    int l = tid & 63;
    int lo = l & 15, q = l >> 4;

    f4v acc[NT];
#pragma unroll
    for (int i = 0; i < NT; ++i) acc[i] = (f4v){0.f, 0.f, 0.f, 0.f};

#pragma unroll
    for (int ks = 0; ks < 4; ++ks) {
        s8v af = *(const s8v*)&Al[(16 * w + lo) * LDK + ks * 32 + q * 8];
#pragma unroll
        for (int nt = 0; nt < NT; ++nt) {
            s8v wf = *(const s8v*)&Wl[(nt * 16 + lo) * LDK + ks * 32 + q * 8];
            acc[nt] = __builtin_amdgcn_mfma_f32_16x16x32_bf16(wf, af, acc[nt], 0, 0, 0);
        }
    }

    int grow = row0 + 16 * w + lo;
    if (grow < N) {
        float dr = dinv[grow];
#pragma unroll
        for (int nt = 0; nt < NT; ++nt) {
            uint2 p;
            p.x = pack2(acc[nt][0] * dr, acc[nt][1] * dr);
            p.y = pack2(acc[nt][2] * dr, acc[nt][3] * dr);
            *(uint2*)(hs + ((size_t)nt * N + grow) * 16 + q * 4) = p;  // plane layout
        }
    }
}

// ---- XCD-affine sliced aggregation:
//      out[i, 16s:16s+16] = dinv[i]*(hs_s[i] + sum_j hs_s[j]) + b[16s:16s+16]
//      slice s = blockIdx & (NSL-1) -> with round-robin block->XCD mapping,
//      each XCD's L2 only caches plane s (3.2 MB, fits 4 MB). ----

template <int C, int NSL, bool RELU, bool OUTBF>
__global__ __launch_bounds__(256) void aggregate_sl(const ushort* __restrict__ hs,
                                                    const float* __restrict__ dinv,
                                                    const int* __restrict__ rowptr,
                                                    const int* __restrict__ csr,
                                                    const float* __restrict__ bias,
                                                    void* __restrict__ out, int N) {
    int bid = blockIdx.x;
    int slice = bid & (NSL - 1);
    int chunk = bid / NSL;
    int tid = threadIdx.x;
    int g = tid >> 2;             // 64 node-groups per block
    int lane = tid & 3;           // 4 lanes x uint2 (8B) = 32B slice row
    int node = chunk * 64 + g;
    if (node >= N) return;

    const uint2* h2 = (const uint2*)(hs + (size_t)slice * N * 16);  // plane: [N][16] bf16
    float accA[4], accB[4];
    {
        uint2 v = h2[(size_t)node * 4 + lane];
        accA[0] = bflo(v.x); accA[1] = bfhi(v.x);
        accA[2] = bflo(v.y); accA[3] = bfhi(v.y);
    }
#pragma unroll
    for (int k = 0; k < 4; ++k) accB[k] = 0.f;

    int beg = rowptr[node];
    int end = rowptr[node + 1];
    int e = beg;
    for (; e + 8 <= end; e += 8) {
        int j[8];
#pragma unroll
        for (int k = 0; k < 8; ++k) j[k] = csr[e + k];
        uint2 v[8];
#pragma unroll
        for (int k = 0; k < 8; ++k) v[k] = h2[(size_t)j[k] * 4 + lane];
#pragma unroll
        for (int k = 0; k < 8; ++k) {
            float* a = (k & 1) ? accB : accA;
            a[0] += bflo(v[k].x); a[1] += bfhi(v[k].x);
            a[2] += bflo(v[k].y); a[3] += bfhi(v[k].y);
        }
    }
    if (e + 4 <= end) {
        int j0 = csr[e], j1 = csr[e + 1], j2 = csr[e + 2], j3 = csr[e + 3];
        uint2 v0 = h2[(size_t)j0 * 4 + lane];
        uint2 v1 = h2[(size_t)j1 * 4 + lane];
        uint2 v2 = h2[(size_t)j2 * 4 + lane];
        uint2 v3 = h2[(size_t)j3 * 4 + lane];
        accA[0] += bflo(v0.x) + bflo(v2.x); accA[1] += bfhi(v0.x) + bfhi(v2.x);
        accA[2] += bflo(v0.y) + bflo(v2.y); accA[3] += bfhi(v0.y) + bfhi(v2.y);
        accB[0] += bflo(v1.x) + bflo(v3.x); accB[1] += bfhi(v1.x) + bfhi(v3.x);
        accB[2] += bflo(v1.y) + bflo(v3.y); accB[3] += bfhi(v1.y) + bfhi(v3.y);
        e += 4;
    }
    for (; e < end; ++e) {
        uint2 v = h2[(size_t)csr[e] * 4 + lane];
        accA[0] += bflo(v.x); accA[1] += bfhi(v.x);
        accA[2] += bflo(v.y); accA[3] += bfhi(v.y);
    }

    float di = dinv[node];
    float4 bv = *(const float4*)(bias + slice * 16 + lane * 4);
    float o[4];
    o[0] = fmaf(di, accA[0] + accB[0], bv.x);
    o[1] = fmaf(di, accA[1] + accB[1], bv.y);
    o[2] = fmaf(di, accA[2] + accB[2], bv.z);
    o[3] = fmaf(di, accA[3] + accB[3], bv.w);
    if (RELU) {
#pragma unroll
        for (int k = 0; k < 4; ++k) o[k] = fmaxf(o[k], 0.f);
    }
    if (OUTBF) {
        uint2 p;
        p.x = pack2(o[0], o[1]);
        p.y = pack2(o[2], o[3]);
        *(uint2*)((ushort*)out + (size_t)node * C + slice * 16 + lane * 4) = p;
    } else {
        *(float4*)((float*)out + (size_t)node * C + slice * 16 + lane * 4) =
            make_float4(o[0], o[1], o[2], o[3]);
    }
}

// ---------------- launch ----------------

extern "C" void kernel_launch(void* const* d_in, const int* in_sizes, int n_in,
                              void* d_out, int out_size, void* d_ws, size_t ws_size,
                              hipStream_t stream) {
    const float* x  = (const float*)d_in[0];
    const int*   ei = (const int*)d_in[1];
    const float* W1 = (const float*)d_in[2];
    const float* b1 = (const float*)d_in[3];
    const float* W2 = (const float*)d_in[4];
    const float* b2 = (const float*)d_in[5];
    float* out = (float*)d_out;

    const int D = 128;
    int N = in_sizes[0] / D;
    int E = in_sizes[1] / 2;
    const int* src = ei;      // edge_index[0] (sources j)
    const int* dst = ei + E;  // edge_index[1] (targets i)

    int nbuck = (N + 255) >> BSHIFT;

    char* ws = (char*)d_ws;
    size_t off = 0;
    auto alloc = [&](size_t bytes) -> void* {
        void* p = ws + off;
        off += (bytes + 255) & ~(size_t)255;
        return p;
    };
    int*    bcnt  = (int*)alloc((size_t)NBUCK_MAX * 4);
    int*    bo    = (int*)alloc((size_t)(NBUCK_MAX + 1) * 4);
    int*    bcur  = (int*)alloc((size_t)NBUCK_MAX * 4);
    int*    rowptr= (int*)alloc((size_t)(N + 1) * 4);
    float*  dinv  = (float*)alloc((size_t)N * 4);
    uint*   eb    = (uint*)alloc((size_t)E * 4);
    int*    csr   = (int*)alloc((size_t)E * 4);
    ushort* wt1   = (ushort*)alloc((size_t)128 * 128 * 2);
    ushort* wt2   = (ushort*)alloc((size_t)64 * 128 * 2);
    ushort* hs1   = (ushort*)alloc((size_t)N * 128 * 2);  // 8 planes [N][16] bf16
    ushort* h1a   = (ushort*)alloc((size_t)N * 128 * 2);  // layer-1 out, row-major bf16
    ushort* hs2   = hs1;  // reuse: 4 planes [N][16] bf16

    int PB = (E + PART_CH - 1) / PART_CH;

    hipMemsetAsync(bcnt, 0, (size_t)NBUCK_MAX * 4, stream);
    hist_k<<<PB, 256, 0, stream>>>(dst, E, nbuck, bcnt);
    bscan_k<<<1, 512, 0, stream>>>(bcnt, nbuck, E, bo, bcur);
    part_k<<<PB, 256, 0, stream>>>(src, dst, E, nbuck, bcur, eb);
    build_k<<<nbuck, 256, 0, stream>>>(eb, bo, N, E, rowptr, dinv, csr);
    wtrans_k<128><<<2, 64, 0, stream>>>(W1, wt1);
    wtrans_k<64><<<1, 64, 0, stream>>>(W2, wt2);

    int gG = (N + 63) / 64;
    int chunks = (N + 63) / 64;
    // layer 1
    gemm_mfma<128, true><<<gG, 256, 0, stream>>>(x, wt1, dinv, hs1, N);
    aggregate_sl<128, 8, true, true><<<chunks * 8, 256, 0, stream>>>(hs1, dinv, rowptr, csr, b1, h1a, N);
    // layer 2
    gemm_mfma<64, false><<<gG, 256, 0, stream>>>(h1a, wt2, dinv, hs2, N);
    aggregate_sl<64, 4, false, false><<<chunks * 4, 256, 0, stream>>>(hs2, dinv, rowptr, csr, b2, out, N);
}